// Round 2
// baseline (1047.840 us; speedup 1.0000x reference)
//
#include <hip/hip_runtime.h>

// Problem constants
#define NB 32
#define NT 1024
#define ND 512
#define NG 256
#define NE 8
#define NV 8192

// ---- workspace layout (bytes) ----
// Xbf   : NB*NT*ND bf16            = 33,554,432
// Wtbf  : NE*NV*ND bf16 (transposed [e][v][d]) = 67,108,864
// sumexp: NB*NT f32                = 131,072
// assign: 32 int, counts: 32 int, nll_sum: 32 f32
#define XBF_BYTES   (33554432)
#define WT_BYTES    (67108864)
#define SE_BYTES    (131072)

typedef float f32x4 __attribute__((ext_vector_type(4)));
typedef __bf16 bf16x8 __attribute__((ext_vector_type(8)));
typedef unsigned int u32_g __attribute__((address_space(1)));
typedef unsigned int u32_l __attribute__((address_space(3)));
typedef unsigned short ushort_t;

__device__ __forceinline__ void g2l16(void* lds, const void* g) {
    // async global->LDS, 16B per lane; LDS dest = wave-uniform base + lane*16
    __builtin_amdgcn_global_load_lds((const u32_g*)g, (u32_l*)lds, 16, 0, 0);
}

__device__ __forceinline__ unsigned short f2bf(float f) {
    unsigned int u = __float_as_uint(f);
    unsigned int r = (u + 0x7fffu + ((u >> 16) & 1u)) >> 16; // RNE
    return (unsigned short)r;
}

// ---------------- K1: router (tiny) ----------------
__global__ void k_router(const float* __restrict__ gate, const float* __restrict__ Wg,
                         const float* __restrict__ bg, float* __restrict__ out,
                         int* __restrict__ assign, int* __restrict__ counts,
                         float* __restrict__ nll_sum) {
    __shared__ float lg[NB][NE];
    __shared__ int lam[NB];
    int tid = threadIdx.x;                 // 256 threads: one per (b,e)
    int b = tid >> 3, e = tid & 7;
    float acc = bg[e];
    const float* gr = gate + b * NG;
    for (int g = 0; g < NG; ++g) acc = fmaf(gr[g], Wg[g * NE + e], acc);
    lg[b][e] = acc;
    if (tid < NB) nll_sum[tid] = 0.f;
    __syncthreads();
    if (tid < NB) {
        float mx = lg[tid][0]; int am = 0;
        for (int j = 1; j < NE; ++j) { float v = lg[tid][j]; if (v > mx) { mx = v; am = j; } }
        float den = 0.f, ex[NE];
        for (int j = 0; j < NE; ++j) { ex[j] = __expf(lg[tid][j] - mx); den += ex[j]; }
        float inv = 1.f / den;
        for (int j = 0; j < NE; ++j) out[1 + NB + tid * NE + j] = ex[j] * inv; // probs
        out[1 + tid] = (float)am;                                             // assignments
        assign[tid] = am;
        lam[tid] = am;
    }
    __syncthreads();
    if (tid == 0) {
        int c[NE] = {0,0,0,0,0,0,0,0};
        for (int i = 0; i < NB; ++i) c[lam[i]]++;
        for (int j = 0; j < NE; ++j) counts[j] = c[j];
        out[0] = 0.f;
    }
}

// ---------------- K2: convert X fp32 -> bf16 ----------------
__global__ void k_convx(const float4* __restrict__ in, ushort_t* __restrict__ out, int n4) {
    int i = blockIdx.x * blockDim.x + threadIdx.x;
    int stride = gridDim.x * blockDim.x;
    for (; i < n4; i += stride) {
        float4 v = in[i];
        ushort4 o;
        o.x = f2bf(v.x); o.y = f2bf(v.y); o.z = f2bf(v.z); o.w = f2bf(v.w);
        ((ushort4*)out)[i] = o;
    }
}

// ---------------- K3: transpose+convert We[e][d][v] -> Wt[e][v][d] bf16 ----------------
__global__ void k_transw(const float* __restrict__ We, ushort_t* __restrict__ Wt) {
    __shared__ float tile[32][33];
    int e = blockIdx.z, d0 = blockIdx.y * 32, v0 = blockIdx.x * 32;
    int tx = threadIdx.x & 31, ty = threadIdx.x >> 5; // 32 x 8
    const float* src = We + (size_t)e * ND * NV;
    for (int j = 0; j < 4; ++j)
        tile[ty + j * 8][tx] = src[(size_t)(d0 + ty + j * 8) * NV + v0 + tx];
    __syncthreads();
    ushort_t* dst = Wt + (size_t)e * NV * ND;
    for (int j = 0; j < 4; ++j)
        dst[(size_t)(v0 + ty + j * 8) * ND + d0 + tx] = f2bf(tile[tx][ty + j * 8]);
}

// ---------------- K4: fused GEMM + exp-sum ----------------
// Block: 256 threads (4 waves), tile BT=64 rows x BV=256 cols, BK=32.
// Wave w owns 64x64 sub-tile at cols w*64 (4x4 of 16x16x32 MFMA).
// Per-row sum of exp(logit+bias) accumulated in registers across all V tiles.
#define BT 64
#define BV 256
#define BK 32

__global__ __launch_bounds__(256, 2)
void k_gemm(const ushort_t* __restrict__ Xbf, const ushort_t* __restrict__ Wtbf,
            const float* __restrict__ be, const int* __restrict__ assign,
            float* __restrict__ sumexp) {
    __shared__ alignas(16) ushort_t lA[BT * BK];   // [row][k], 4 KB
    __shared__ alignas(16) ushort_t lB[BV * BK];   // [vrow][k], 16 KB
    __shared__ float lws[4][BT];                   // per-wave row sums

    const int tid  = threadIdx.x;
    const int wave = tid >> 6, lane = tid & 63;
    const int q = lane >> 4, ln = lane & 15;
    const int b  = blockIdx.x >> 4;
    const int t0 = (blockIdx.x & 15) * BT;
    const int e  = assign[b];
    const size_t eV = (size_t)e * NV;

    // staging source pointers (per-thread 16B chunk)
    const ushort_t* gA  = Xbf  + ((size_t)(b * NT + t0 + (tid >> 2))) * ND + (tid & 3) * 8;
    const ushort_t* gB0 = Wtbf + (eV + (size_t)(tid >> 2)) * ND + (tid & 3) * 8;
    char* lAbase = (char*)lA + wave * 1024; // wave-uniform LDS base

    float partial[16];
#pragma unroll
    for (int i = 0; i < 16; ++i) partial[i] = 0.f;

    const float LOG2E = 1.44269504088896f;

    for (int v0 = 0; v0 < NV; v0 += BV) {
        f32x4 acc[4][4];
#pragma unroll
        for (int mt = 0; mt < 4; ++mt)
#pragma unroll
            for (int nt = 0; nt < 4; ++nt) acc[mt][nt] = (f32x4){0.f, 0.f, 0.f, 0.f};

        for (int k0 = 0; k0 < ND; k0 += BK) {
            __syncthreads();                            // LDS safe to overwrite
            g2l16(lAbase, gA + k0);                     // A tile: 4 KB
#pragma unroll
            for (int j = 0; j < 4; ++j)                 // B tile: 16 KB
                g2l16((char*)lB + j * 4096 + wave * 1024,
                      gB0 + (size_t)(v0 + j * 64) * ND + k0);
            __syncthreads();                            // drain vmcnt + barrier

            bf16x8 af[4], bfr[4];
#pragma unroll
            for (int mt = 0; mt < 4; ++mt)
                af[mt] = *(const bf16x8*)&lA[(mt * 16 + ln) * BK + q * 8];
#pragma unroll
            for (int nt = 0; nt < 4; ++nt)
                bfr[nt] = *(const bf16x8*)&lB[(wave * 64 + nt * 16 + ln) * BK + q * 8];
#pragma unroll
            for (int mt = 0; mt < 4; ++mt)
#pragma unroll
                for (int nt = 0; nt < 4; ++nt)
                    acc[mt][nt] = __builtin_amdgcn_mfma_f32_16x16x32_bf16(
                        af[mt], bfr[nt], acc[mt][nt], 0, 0, 0);
        }
        // epilogue: accumulate exp(logit + bias) per row
#pragma unroll
        for (int nt = 0; nt < 4; ++nt) {
            int col = v0 + wave * 64 + nt * 16 + ln;
            float eb = be[eV + col] * LOG2E;
#pragma unroll
            for (int mt = 0; mt < 4; ++mt)
#pragma unroll
                for (int r = 0; r < 4; ++r)
                    partial[mt * 4 + r] += exp2f(fmaf(acc[mt][nt][r], LOG2E, eb));
        }
    }

    // reduce across the 16 column-lanes (rows identical for ln=0..15 within a quad)
#pragma unroll
    for (int i = 0; i < 16; ++i) {
        float p = partial[i];
        p += __shfl_xor(p, 1); p += __shfl_xor(p, 2);
        p += __shfl_xor(p, 4); p += __shfl_xor(p, 8);
        partial[i] = p;
    }
    if (ln == 0) {
#pragma unroll
        for (int mt = 0; mt < 4; ++mt)
#pragma unroll
            for (int r = 0; r < 4; ++r)
                lws[wave][mt * 16 + q * 4 + r] = partial[mt * 4 + r];
    }
    __syncthreads();
    if (tid < BT) {
        float s = lws[0][tid] + lws[1][tid] + lws[2][tid] + lws[3][tid];
        sumexp[(size_t)b * NT + t0 + tid] = s;
    }
}

// ---------------- K5: target logit + nll accumulate ----------------
__global__ void k_target(const ushort_t* __restrict__ Xbf, const ushort_t* __restrict__ Wtbf,
                         const float* __restrict__ be, const int* __restrict__ assign,
                         const int* __restrict__ tgt, const float* __restrict__ sumexp,
                         float* __restrict__ nll_sum) {
    int wave = threadIdx.x >> 6, lane = threadIdx.x & 63;
    int wg = blockIdx.x * 4 + wave;       // one wave per (b,t)
    int b = wg >> 10, t = wg & 1023;
    int e = assign[b];
    int id = tgt[b * NT + t];
    const bf16x8 xv = *(const bf16x8*)(Xbf + (size_t)(b * NT + t) * ND + lane * 8);
    const bf16x8 wv = *(const bf16x8*)(Wtbf + ((size_t)e * NV + id) * ND + lane * 8);
    float s = 0.f;
#pragma unroll
    for (int i = 0; i < 8; ++i) s = fmaf((float)xv[i], (float)wv[i], s);
    for (int off = 32; off; off >>= 1) s += __shfl_down(s, off);
    if (lane == 0) {
        float lt = s + be[(size_t)e * NV + id];
        float nll = __logf(sumexp[(size_t)b * NT + t]) - lt;
        atomicAdd(&nll_sum[b], nll);
    }
}

// ---------------- K6: final combine ----------------
__global__ void k_final(const float* __restrict__ nll_sum, const int* __restrict__ assign,
                        const int* __restrict__ counts, float* __restrict__ out) {
    int tid = threadIdx.x; // 64 threads, one wave
    float contrib = 0.f;
    if (tid < NB) {
        float ce = nll_sum[tid] * (1.0f / (float)NT);
        contrib = ce / (float)counts[assign[tid]];
    }
    for (int off = 32; off; off >>= 1) contrib += __shfl_down(contrib, off);
    if (tid == 0) out[0] = contrib;
}

extern "C" void kernel_launch(void* const* d_in, const int* in_sizes, int n_in,
                              void* d_out, int out_size, void* d_ws, size_t ws_size,
                              hipStream_t stream) {
    const float* gate = (const float*)d_in[0];
    const float* X    = (const float*)d_in[1];
    const float* Wg   = (const float*)d_in[2];
    const float* bg   = (const float*)d_in[3];
    const float* We   = (const float*)d_in[4];
    const float* be   = (const float*)d_in[5];
    const int*   tgt  = (const int*)d_in[6];
    float* out = (float*)d_out;

    char* ws = (char*)d_ws;
    ushort_t* Xbf    = (ushort_t*)ws;
    ushort_t* Wtbf   = (ushort_t*)(ws + XBF_BYTES);
    float*    sumexp = (float*)(ws + XBF_BYTES + WT_BYTES);
    int*      assign = (int*)(ws + XBF_BYTES + WT_BYTES + SE_BYTES);
    int*      counts = assign + 32;
    float*    nll    = (float*)(assign + 64);

    k_router<<<1, 256, 0, stream>>>(gate, Wg, bg, out, assign, counts, nll);
    k_convx<<<4096, 256, 0, stream>>>((const float4*)X, Xbf, NB * NT * ND / 4);
    k_transw<<<dim3(NV / 32, ND / 32, NE), 256, 0, stream>>>(We, Wtbf);
    k_gemm<<<NB * (NT / BT), 256, 0, stream>>>(Xbf, Wtbf, be, assign, sumexp);
    k_target<<<NB * NT / 4, 256, 0, stream>>>(Xbf, Wtbf, be, assign, tgt, sumexp, nll);
    k_final<<<1, 64, 0, stream>>>(nll, assign, counts, out);
}

// Round 3
// 745.241 us; speedup vs baseline: 1.4060x; 1.4060x over previous
//
#include <hip/hip_runtime.h>

// Problem constants
#define NB 32
#define NT 1024
#define ND 512
#define NG 256
#define NE 8
#define NV 8192
#define NROW (NB * NT)   // 32768 output rows

// ---- workspace layout (bytes) ----
#define XBF_BYTES   (33554432)   // NB*NT*ND bf16
#define WT_BYTES    (67108864)   // NE*NV*ND bf16 transposed [e][v][d]
#define PSUM_BYTES  (8388608)    // 64 colTiles x 32768 rows f32 partial sumexp
#define TL_BYTES    (131072)     // NB*NT f32 target logits

typedef float f32x4 __attribute__((ext_vector_type(4)));
typedef __bf16 bf16x8 __attribute__((ext_vector_type(8)));
typedef unsigned int u32_g __attribute__((address_space(1)));
typedef unsigned int u32_l __attribute__((address_space(3)));
typedef unsigned short ushort_t;

__device__ __forceinline__ void g2l16(void* lds, const void* g) {
    // async global->LDS, 16B per lane; LDS dest = wave-uniform base + lane*16
    __builtin_amdgcn_global_load_lds((const u32_g*)g, (u32_l*)lds, 16, 0, 0);
}

__device__ __forceinline__ unsigned short f2bf(float f) {
    unsigned int u = __float_as_uint(f);
    unsigned int r = (u + 0x7fffu + ((u >> 16) & 1u)) >> 16; // RNE
    return (unsigned short)r;
}

// ---------------- K1: router (tiny) ----------------
__global__ void k_router(const float* __restrict__ gate, const float* __restrict__ Wg,
                         const float* __restrict__ bg, float* __restrict__ out,
                         int* __restrict__ assign, int* __restrict__ counts) {
    __shared__ float lg[NB][NE];
    __shared__ int lam[NB];
    int tid = threadIdx.x;                 // 256 threads: one per (b,e)
    int b = tid >> 3, e = tid & 7;
    float acc = bg[e];
    const float* gr = gate + b * NG;
    for (int g = 0; g < NG; ++g) acc = fmaf(gr[g], Wg[g * NE + e], acc);
    lg[b][e] = acc;
    __syncthreads();
    if (tid < NB) {
        float mx = lg[tid][0]; int am = 0;
        for (int j = 1; j < NE; ++j) { float v = lg[tid][j]; if (v > mx) { mx = v; am = j; } }
        float den = 0.f, ex[NE];
        for (int j = 0; j < NE; ++j) { ex[j] = __expf(lg[tid][j] - mx); den += ex[j]; }
        float inv = 1.f / den;
        for (int j = 0; j < NE; ++j) out[1 + NB + tid * NE + j] = ex[j] * inv; // probs
        out[1 + tid] = (float)am;                                             // assignments
        assign[tid] = am;
        lam[tid] = am;
    }
    __syncthreads();
    if (tid == 0) {
        int c[NE] = {0,0,0,0,0,0,0,0};
        for (int i = 0; i < NB; ++i) c[lam[i]]++;
        for (int j = 0; j < NE; ++j) counts[j] = c[j];
        out[0] = 0.f;
    }
}

// ---------------- K2: convert X fp32 -> bf16 ----------------
__global__ void k_convx(const float4* __restrict__ in, ushort_t* __restrict__ out, int n4) {
    int i = blockIdx.x * blockDim.x + threadIdx.x;
    int stride = gridDim.x * blockDim.x;
    for (; i < n4; i += stride) {
        float4 v = in[i];
        ushort4 o;
        o.x = f2bf(v.x); o.y = f2bf(v.y); o.z = f2bf(v.z); o.w = f2bf(v.w);
        ((ushort4*)out)[i] = o;
    }
}

// ---------------- K3: transpose+convert We[e][d][v] -> Wt[e][v][d] bf16 ----------------
__global__ void k_transw(const float* __restrict__ We, ushort_t* __restrict__ Wt) {
    __shared__ float tile[32][33];
    int e = blockIdx.z, d0 = blockIdx.y * 32, v0 = blockIdx.x * 32;
    int tx = threadIdx.x & 31, ty = threadIdx.x >> 5; // 32 x 8
    const float* src = We + (size_t)e * ND * NV;
    for (int j = 0; j < 4; ++j)
        tile[ty + j * 8][tx] = src[(size_t)(d0 + ty + j * 8) * NV + v0 + tx];
    __syncthreads();
    ushort_t* dst = Wt + (size_t)e * NV * ND;
    for (int j = 0; j < 4; ++j)
        dst[(size_t)(v0 + ty + j * 8) * ND + d0 + tx] = f2bf(tile[tx][ty + j * 8]);
}

// ---------------- K4: fused GEMM + exp partial-sum (m97 structure) ----------------
// 128x128 output tile, 256 threads = 4 waves in 2x2, each wave 64x64 (4x4 MFMA).
// Grid: colTile-major so 256 consecutive blocks share one B tile (L2 reuse).
// Per-block: partial sumexp over its 128 columns -> psum[ct][row].
#define BM 128
#define BN 128
#define BK 32

__global__ __launch_bounds__(256, 4)
void k_gemm(const ushort_t* __restrict__ Xbf, const ushort_t* __restrict__ Wtbf,
            const float* __restrict__ be, const int* __restrict__ assign,
            float* __restrict__ psum) {
    __shared__ alignas(16) ushort_t lA[BM * BK];   // [row][k], 8 KB
    __shared__ alignas(16) ushort_t lB[BN * BK];   // [vrow][k], 8 KB
    __shared__ float lws[4][64];

    const int tid  = threadIdx.x;
    const int wave = tid >> 6, lane = tid & 63;
    const int q = lane >> 4, ln = lane & 15;
    const int wr = wave >> 1, wc = wave & 1;

    const int ct = blockIdx.x >> 8;        // 0..63  column tile
    const int rt = blockIdx.x & 255;       // 0..255 row tile
    const int b  = rt >> 3;
    const int t0 = (rt & 7) * BM;
    const int v0 = ct * BN;
    const int e  = assign[b];
    const size_t eV = (size_t)e * NV;

    const ushort_t* gA = Xbf  + ((size_t)(b * NT + t0 + (tid >> 2))) * ND + (tid & 3) * 8;
    const ushort_t* gB = Wtbf + (eV + v0 + (size_t)(tid >> 2)) * ND + (tid & 3) * 8;
    char* lAb = (char*)lA + wave * 1024;   // wave-uniform LDS bases
    char* lBb = (char*)lB + wave * 1024;

    f32x4 acc[4][4];
#pragma unroll
    for (int mt = 0; mt < 4; ++mt)
#pragma unroll
        for (int nt = 0; nt < 4; ++nt) acc[mt][nt] = (f32x4){0.f, 0.f, 0.f, 0.f};

    for (int k0 = 0; k0 < ND; k0 += BK) {
        __syncthreads();                               // LDS safe to overwrite
        g2l16(lAb, gA + k0);                           // A rows 0..63
        g2l16(lAb + 4096, gA + (size_t)64 * ND + k0);  // A rows 64..127
        g2l16(lBb, gB + k0);                           // B rows 0..63
        g2l16(lBb + 4096, gB + (size_t)64 * ND + k0);  // B rows 64..127
        __syncthreads();                               // drain vmcnt + barrier

        bf16x8 af[4], bfv[4];
#pragma unroll
        for (int mt = 0; mt < 4; ++mt)
            af[mt] = *(const bf16x8*)&lA[(wr * 64 + mt * 16 + ln) * BK + q * 8];
#pragma unroll
        for (int nt = 0; nt < 4; ++nt)
            bfv[nt] = *(const bf16x8*)&lB[(wc * 64 + nt * 16 + ln) * BK + q * 8];
#pragma unroll
        for (int mt = 0; mt < 4; ++mt)
#pragma unroll
            for (int nt = 0; nt < 4; ++nt)
                acc[mt][nt] = __builtin_amdgcn_mfma_f32_16x16x32_bf16(
                    af[mt], bfv[nt], acc[mt][nt], 0, 0, 0);
    }

    // epilogue: partial[16] = per-(mt,r) row sums of exp(logit+bias) over this tile's cols
    const float LOG2E = 1.44269504088896f;
    float partial[16];
#pragma unroll
    for (int i = 0; i < 16; ++i) partial[i] = 0.f;
#pragma unroll
    for (int nt = 0; nt < 4; ++nt) {
        int col = v0 + wc * 64 + nt * 16 + ln;
        float eb = be[eV + col] * LOG2E;
#pragma unroll
        for (int mt = 0; mt < 4; ++mt)
#pragma unroll
            for (int r = 0; r < 4; ++r)
                partial[mt * 4 + r] += exp2f(fmaf(acc[mt][nt][r], LOG2E, eb));
    }
    // reduce across the 16 column-lanes
#pragma unroll
    for (int i = 0; i < 16; ++i) {
        float p = partial[i];
        p += __shfl_xor(p, 1); p += __shfl_xor(p, 2);
        p += __shfl_xor(p, 4); p += __shfl_xor(p, 8);
        partial[i] = p;
    }
    if (ln == 0) {
#pragma unroll
        for (int mt = 0; mt < 4; ++mt)
#pragma unroll
            for (int r = 0; r < 4; ++r)
                lws[wave][mt * 16 + q * 4 + r] = partial[mt * 4 + r];
    }
    __syncthreads();
    if (tid < BM) {
        int half = tid >> 6, idx = tid & 63;           // half == wr of this row
        float s = lws[half * 2][idx] + lws[half * 2 + 1][idx];
        psum[(size_t)ct * NROW + rt * BM + tid] = s;
    }
}

// ---------------- K5: target logit (no atomics) ----------------
__global__ void k_target(const ushort_t* __restrict__ Xbf, const ushort_t* __restrict__ Wtbf,
                         const float* __restrict__ be, const int* __restrict__ assign,
                         const int* __restrict__ tgt, float* __restrict__ tl) {
    int wave = threadIdx.x >> 6, lane = threadIdx.x & 63;
    int wg = blockIdx.x * 4 + wave;       // one wave per (b,t)
    int b = wg >> 10, t = wg & 1023;
    int e = assign[b];
    int id = tgt[b * NT + t];
    const bf16x8 xv = *(const bf16x8*)(Xbf + (size_t)(b * NT + t) * ND + lane * 8);
    const bf16x8 wv = *(const bf16x8*)(Wtbf + ((size_t)e * NV + id) * ND + lane * 8);
    float s = 0.f;
#pragma unroll
    for (int i = 0; i < 8; ++i) s = fmaf((float)xv[i], (float)wv[i], s);
    for (int off = 32; off; off >>= 1) s += __shfl_down(s, off);
    if (lane == 0) tl[b * NT + t] = s + be[(size_t)e * NV + id];
}

// ---------------- K6: reduce psum -> nll[b] ----------------
__global__ void k_loss(const float* __restrict__ psum, const float* __restrict__ tl,
                       float* __restrict__ nll) {
    int b = blockIdx.x, tid = threadIdx.x;   // 32 blocks x 256 threads
    float acc = 0.f;
#pragma unroll
    for (int j = 0; j < 4; ++j) {
        int t = j * 256 + tid;
        float s = 0.f;
        for (int ct = 0; ct < 64; ++ct) s += psum[(size_t)ct * NROW + b * NT + t];
        acc += __logf(s) - tl[b * NT + t];
    }
    // block reduce 256 -> 1
    __shared__ float red[4];
    for (int off = 32; off; off >>= 1) acc += __shfl_down(acc, off);
    if ((tid & 63) == 0) red[tid >> 6] = acc;
    __syncthreads();
    if (tid == 0) nll[b] = red[0] + red[1] + red[2] + red[3];
}

// ---------------- K7: final combine ----------------
__global__ void k_final(const float* __restrict__ nll_sum, const int* __restrict__ assign,
                        const int* __restrict__ counts, float* __restrict__ out) {
    int tid = threadIdx.x; // 64 threads, one wave
    float contrib = 0.f;
    if (tid < NB) {
        float ce = nll_sum[tid] * (1.0f / (float)NT);
        contrib = ce / (float)counts[assign[tid]];
    }
    for (int off = 32; off; off >>= 1) contrib += __shfl_down(contrib, off);
    if (tid == 0) out[0] = contrib;
}

extern "C" void kernel_launch(void* const* d_in, const int* in_sizes, int n_in,
                              void* d_out, int out_size, void* d_ws, size_t ws_size,
                              hipStream_t stream) {
    const float* gate = (const float*)d_in[0];
    const float* X    = (const float*)d_in[1];
    const float* Wg   = (const float*)d_in[2];
    const float* bg   = (const float*)d_in[3];
    const float* We   = (const float*)d_in[4];
    const float* be   = (const float*)d_in[5];
    const int*   tgt  = (const int*)d_in[6];
    float* out = (float*)d_out;

    char* ws = (char*)d_ws;
    ushort_t* Xbf  = (ushort_t*)ws;
    ushort_t* Wtbf = (ushort_t*)(ws + XBF_BYTES);
    float*    psum = (float*)(ws + XBF_BYTES + WT_BYTES);
    float*    tl   = (float*)(ws + XBF_BYTES + WT_BYTES + PSUM_BYTES);
    int*      assign = (int*)(ws + XBF_BYTES + WT_BYTES + PSUM_BYTES + TL_BYTES);
    int*      counts = assign + 32;
    float*    nll    = (float*)(assign + 64);

    k_router<<<1, 256, 0, stream>>>(gate, Wg, bg, out, assign, counts);
    k_convx<<<4096, 256, 0, stream>>>((const float4*)X, Xbf, NB * NT * ND / 4);
    k_transw<<<dim3(NV / 32, ND / 32, NE), 256, 0, stream>>>(We, Wtbf);
    k_gemm<<<(NROW / BM) * (NV / BN), 256, 0, stream>>>(Xbf, Wtbf, be, assign, psum);
    k_target<<<NB * NT / 4, 256, 0, stream>>>(Xbf, Wtbf, be, assign, tgt, tl);
    k_loss<<<NB, 256, 0, stream>>>(psum, tl, nll);
    k_final<<<1, 64, 0, stream>>>(nll, assign, counts, out);
}